// Round 11
// baseline (42.066 us; speedup 1.0000x reference)
//
#include <hip/hip_runtime.h>

#define NTHR 256
#define TB 16

typedef __attribute__((ext_vector_type(8))) short bf16x8;
typedef __attribute__((ext_vector_type(4))) float f32x4;
typedef float4 f4;
typedef unsigned short u16;

__device__ __forceinline__ u16 f2b(float x) {
  union { float f; unsigned u; } v; v.f = x;
  unsigned r = (v.u + 0x7fffu + ((v.u >> 16) & 1u)) >> 16;
  return (u16)r;
}
__device__ __forceinline__ float b2f(u16 u) {
  union { unsigned u; float f; } v; v.u = ((unsigned)u) << 16;
  return v.f;
}
__device__ __forceinline__ unsigned pack2(float a, float b) {
  return (unsigned)f2b(a) | ((unsigned)f2b(b) << 16);
}
__device__ __forceinline__ unsigned cvtpk(float lo, float hi) {
  unsigned r;
  asm("v_cvt_pk_bf16_f32 %0, %1, %2" : "=v"(r) : "v"(lo), "v"(hi));
  return r;
}

#define MFMA_B(A, B, C) __builtin_amdgcn_mfma_f32_16x16x32_bf16(A, B, C, 0, 0, 0)

// ---------------- prep: 16x16x32-fragment-ordered bf16 weights (r9 layout) ----
// BTf : frag_id = (a*10+kt)*9+p ; lane l, 8 k's: k' = kt*32+(l>>4)*8+j, col s=l&15
//       k' = q*18+r; k'>=306 or r==17 -> 0.
// UcTf: frag_id = (c*4+a)*8+kt;  k = kt*32+(l>>4)*8+j, col r = l&15.
// UOTf: frag_id = a*16+ht;       k = (l>>4)*8+j (k>=16 -> 0), col h = ht*16+(l&15).
extern "C" __global__ void hosvd_prep(const float* __restrict__ U,
                                      const float* __restrict__ T,
                                      const float* __restrict__ UO,
                                      unsigned* __restrict__ ws32) {
  int id = blockIdx.x * 256 + threadIdx.x;
  if (id < 92160) {                       // BTf: 23040 frags * 4 u32
    int j2 = id & 3, frag = id >> 2;
    int l = frag & 63, f2 = frag >> 6;    // f2 = (a*10+kt)*9+p
    int p = f2 % 9, akt = f2 / 9;
    int kt = akt % 10, a = akt / 10;
    int s = l & 15;
    float v[2];
    #pragma unroll
    for (int j = 0; j < 2; ++j) {
      int kp = kt * 32 + (l >> 4) * 8 + j2 * 2 + j;
      float x = 0.f;
      if (kp < 306) {
        int q = (unsigned)kp / 18u, r = kp - q * 18;
        if (r < 17) x = T[(((a * 9 + p) * 17 + q) * 17 + r) * 16 + s];
      }
      v[j] = x;
    }
    ws32[id] = pack2(v[0], v[1]);
  } else if (id < 108544) {               // UcTf: 4096 frags * 4 u32
    int rel = id - 92160;
    int j2 = rel & 3, frag = rel >> 2;
    int l = frag & 63, f2 = frag >> 6;
    int kt = f2 & 7, g = f2 >> 3;
    int a = g & 3, c = g >> 2;
    int rr = l & 15;
    int k = kt * 32 + (l >> 4) * 8 + j2 * 2;
    float v0 = U[((c * 4 + a) * 256 + k + 0) * 16 + rr];
    float v1 = U[((c * 4 + a) * 256 + k + 1) * 16 + rr];
    ws32[id] = pack2(v0, v1);
  } else if (id < 124928) {               // UOTf: 4096 frags * 4 u32
    int rel = id - 108544;
    int j2 = rel & 3, frag = rel >> 2;
    int l = frag & 63, f2 = frag >> 6;
    int ht = f2 & 15, a = f2 >> 4;
    int h = ht * 16 + (l & 15);
    int k = (l >> 4) * 8 + j2 * 2;
    float v0 = (k + 0 < 16) ? UO[(a * 16 + k + 0) * 256 + h] : 0.f;
    float v1 = (k + 1 < 16) ? UO[(a * 16 + k + 1) * 256 + h] : 0.f;
    ws32[id] = pack2(v0, v1);
  }
}

// ---------------- main fused kernel ----------------
// TB=16, 256 thr (4 waves), grid 1024 -> 4 blocks/CU. 3-barrier skeleton.
// LDS 34752 B:
//  s_u   [11424] u16: nh [16][520] | Ut f32[1024] @8320 | te f32[528] @10368
//  s_ch  [16][164] u16: h[row][c*80+a*20+idx]; idx16=1.0, idx17..19=0 sentinels
//  s_tpt [36][16] f32: tp transposed [a*9+p][row]; p=8 row = 1.0 sentinel
//  s_g   [16][136] u16: [row][a*32+s], slots 16..31 zero (K-pad for phase E)
extern "C" __global__ __launch_bounds__(NTHR, 4)
void hosvd_main(const float* __restrict__ nh, const float* __restrict__ te,
                const float* __restrict__ bw, const float* __restrict__ Ut,
                const float* __restrict__ bt, const float* __restrict__ bO,
                const u16* __restrict__ BTf, const u16* __restrict__ UcTf,
                const u16* __restrict__ UOTf, float* __restrict__ out) {
  __shared__ __align__(16) u16   s_u[11424];
  __shared__ __align__(16) u16   s_ch[TB * 164];
  __shared__ __align__(16) float s_tpt[36 * 16];
  __shared__ __align__(16) u16   s_g[TB * 136];

  const int t = threadIdx.x;
  const int ib0 = blockIdx.x * TB;
  const int w = t >> 6, l = t & 63;
  const int rl = l & 15, q = l >> 4;

  float* UtL = (float*)&s_u[8320];      // 1024 f32
  float* teL = (float*)&s_u[10368];     // 528 f32 (16 x 33)

  //---- sentinels ----
  if (t < 128) {  // s_ch idx 16..19 = {1.0, 0, 0, 0} per (row,c,a)
    const int row = t >> 3, cc = (t >> 2) & 1, aa = t & 3;
    *(uint2*)&s_ch[row * 164 + cc * 80 + aa * 20 + 16] = make_uint2(0x3F80u, 0u);
  }
  if (t < 64) {   // s_tpt p=8 row = 1.0
    const int aa = t >> 4, row = t & 15;
    s_tpt[(aa * 9 + 8) * 16 + row] = 1.0f;
  }

  //---- stage: te -> teL (16x33), Ut -> UtL, nh -> s_u bf16 [16][520] ----
  if (t < 128) {
    const int row = t >> 3, k4 = t & 7;
    f4 v = *(const f4*)&te[(size_t)(ib0 + row) * 32 + k4 * 4];
    float* d = &teL[row * 33 + k4 * 4];
    d[0] = v.x; d[1] = v.y; d[2] = v.z; d[3] = v.w;
  }
  *(f4*)&UtL[t * 4] = *(const f4*)&Ut[t * 4];     // 256 f4 = all of Ut
  for (int lp = t; lp < 2048; lp += NTHR) {
    const int row = lp >> 7, rem = lp & 127;
    const int c = rem >> 6, k0 = (rem & 63) * 4;
    f4 v = *(const f4*)&nh[((size_t)(ib0 + row) * 2 + c) * 256 + k0];
    *(uint2*)&s_u[row * 520 + c * 256 + k0] =
        make_uint2(cvtpk(v.x, v.y), cvtpk(v.z, v.w));
  }
  __syncthreads();   // barrier 1

  //---- Phase C (waves 0-1, c=w) || Phase B (waves 2-3) ----
  if (w < 2) {
    const int c = w;
    bf16x8 Af[8];
    #pragma unroll
    for (int kt = 0; kt < 8; ++kt)
      Af[kt] = *(const bf16x8*)&s_u[rl * 520 + c * 256 + kt * 32 + 8 * q];
    #pragma unroll
    for (int a = 0; a < 4; ++a) {
      const u16* u0 = &UcTf[((size_t)((c * 4 + a) * 8) * 64 + l) * 8];
      f32x4 ac = {0.f, 0.f, 0.f, 0.f};
      #pragma unroll
      for (int kt = 0; kt < 8; ++kt) {
        bf16x8 Bv = *(const bf16x8*)(u0 + kt * 512);
        ac = MFMA_B(Af[kt], Bv, ac);
      }
      const float bias = bw[(c * 4 + a) * 16 + rl];
      #pragma unroll
      for (int reg = 0; reg < 4; ++reg)
        s_ch[(4 * q + reg) * 164 + c * 80 + a * 20 + rl] = f2b(ac[reg] + bias);
    }
  } else {
    const int t2 = t - 128;               // 0..127
    const int i = t2 >> 3, off = (t2 & 7) * 4;
    float ac0 = bt[off], ac1 = bt[off + 1], ac2 = bt[off + 2], ac3 = bt[off + 3];
    #pragma unroll
    for (int k = 0; k < 32; ++k) {
      const float tv = teL[i * 33 + k];
      f4 u = *(const f4*)&UtL[k * 32 + off];
      ac0 = fmaf(tv, u.x, ac0);
      ac1 = fmaf(tv, u.y, ac1);
      ac2 = fmaf(tv, u.z, ac2);
      ac3 = fmaf(tv, u.w, ac3);
    }
    #pragma unroll
    for (int jj = 0; jj < 4; ++jj) {
      const int o2 = off + jj;
      const float v = (jj == 0) ? ac0 : (jj == 1) ? ac1 : (jj == 2) ? ac2 : ac3;
      s_tpt[((o2 >> 3) * 9 + (o2 & 7)) * 16 + i] = v;
    }
  }
  __syncthreads();   // barrier 2: s_ch + s_tpt ready

  //---- Core: wave a = w, FULL K (10 kt x 9 p), in-reg A from s_ch ----
  {
    const int a = w;
    const u16* h1g = &s_ch[rl * 164 + a * 20];
    const u16* h2g = h1g + 80;

    f32x4 acc[9];
    #pragma unroll
    for (int p = 0; p < 9; ++p) acc[p] = (f32x4){0.f, 0.f, 0.f, 0.f};

    __builtin_amdgcn_s_setprio(1);
    #pragma unroll
    for (int kt = 0; kt < 10; ++kt) {
      const u16* bp = &BTf[(size_t)((a * 10 + kt) * 9) * 512 + l * 8];
      bf16x8 B0 = *(const bf16x8*)(bp + 0 * 512);
      bf16x8 B1 = *(const bf16x8*)(bp + 1 * 512);
      bf16x8 B2 = *(const bf16x8*)(bp + 2 * 512);
      bf16x8 B3 = *(const bf16x8*)(bp + 3 * 512);
      bf16x8 B4 = *(const bf16x8*)(bp + 4 * 512);
      bf16x8 B5 = *(const bf16x8*)(bp + 5 * 512);
      bf16x8 B6 = *(const bf16x8*)(bp + 6 * 512);
      bf16x8 B7 = *(const bf16x8*)(bp + 7 * 512);
      bf16x8 B8 = *(const bf16x8*)(bp + 8 * 512);

      // A frag: O[row=rl][k'], k' = kt*32 + 8q + j
      const int k0 = kt * 32 + 8 * q;
      const unsigned q0 = (unsigned)k0 / 18u;
      const int r0 = k0 - (int)q0 * 18;
      const int brk = 18 - r0;
      const float h1a = b2f(h1g[q0]);
      const float h1b = b2f(h1g[q0 + 1]);   // slots <=19 zero-init'd
      float hv[8];
      #pragma unroll
      for (int j = 0; j < 8; ++j) {
        int rr = r0 + j;
        rr = (rr >= 18) ? rr - 18 : rr;
        const float h2v = b2f(h2g[rr]);
        hv[j] = ((j < brk) ? h1a : h1b) * h2v;
      }
      union { unsigned u[4]; bf16x8 v; } Au;
      Au.u[0] = cvtpk(hv[0], hv[1]);
      Au.u[1] = cvtpk(hv[2], hv[3]);
      Au.u[2] = cvtpk(hv[4], hv[5]);
      Au.u[3] = cvtpk(hv[6], hv[7]);

      acc[0] = MFMA_B(Au.v, B0, acc[0]);
      acc[1] = MFMA_B(Au.v, B1, acc[1]);
      acc[2] = MFMA_B(Au.v, B2, acc[2]);
      acc[3] = MFMA_B(Au.v, B3, acc[3]);
      acc[4] = MFMA_B(Au.v, B4, acc[4]);
      acc[5] = MFMA_B(Au.v, B5, acc[5]);
      acc[6] = MFMA_B(Au.v, B6, acc[6]);
      acc[7] = MFMA_B(Au.v, B7, acc[7]);
      acc[8] = MFMA_B(Au.v, B8, acc[8]);
    }
    __builtin_amdgcn_s_setprio(0);

    //-- h0-weighted fold + direct s_g write (full K -> no reduce) --
    float gp[4] = {0.f, 0.f, 0.f, 0.f};
    #pragma unroll
    for (int p = 0; p < 9; ++p) {
      f4 tv = *(const f4*)&s_tpt[(a * 9 + p) * 16 + 4 * q];
      gp[0] = fmaf(tv.x, acc[p][0], gp[0]);
      gp[1] = fmaf(tv.y, acc[p][1], gp[1]);
      gp[2] = fmaf(tv.z, acc[p][2], gp[2]);
      gp[3] = fmaf(tv.w, acc[p][3], gp[3]);
    }
    #pragma unroll
    for (int reg = 0; reg < 4; ++reg) {
      const int row2 = 4 * q + reg;
      s_g[row2 * 136 + a * 32 + rl]      = f2b(gp[reg]);
      s_g[row2 * 136 + a * 32 + 16 + rl] = 0;   // zero K-pad for phase E
    }
  }
  __syncthreads();   // barrier 3: s_g ready

  //---- Phase E: wave e = w handles ht {4e..4e+3} for all 4 a ----
  {
    const int e = w;
    #pragma unroll
    for (int a = 0; a < 4; ++a) {
      bf16x8 A = *(const bf16x8*)&s_g[rl * 136 + a * 32 + 8 * q];
      #pragma unroll
      for (int j = 0; j < 4; ++j) {
        const int ht = e * 4 + j;
        bf16x8 Bv = *(const bf16x8*)&UOTf[((size_t)(a * 16 + ht) * 64 + l) * 8];
        const float bias = bO[a * 256 + ht * 16 + rl];
        f32x4 accE = {bias, bias, bias, bias};
        accE = MFMA_B(A, Bv, accE);
        #pragma unroll
        for (int reg = 0; reg < 4; ++reg)
          out[(size_t)(ib0 + 4 * q + reg) * 1024 + a * 256 + ht * 16 + rl] =
              accE[reg];
      }
    }
  }
}

extern "C" void kernel_launch(void* const* d_in, const int* in_sizes, int n_in,
                              void* d_out, int out_size, void* d_ws, size_t ws_size,
                              hipStream_t stream) {
  const float* nh = (const float*)d_in[0];
  const float* te = (const float*)d_in[1];
  const float* U  = (const float*)d_in[2];
  const float* bw = (const float*)d_in[3];
  const float* Ut = (const float*)d_in[4];
  const float* bt = (const float*)d_in[5];
  const float* T  = (const float*)d_in[6];
  const float* UO = (const float*)d_in[7];
  const float* bO = (const float*)d_in[8];
  float* out = (float*)d_out;

  unsigned* ws32 = (unsigned*)d_ws;
  hipLaunchKernelGGL(hosvd_prep, dim3(488), dim3(256), 0, stream, U, T, UO, ws32);

  const u16* BTf  = (const u16*)d_ws;         // 184320 u16
  const u16* UcTf = BTf + 184320;             // 32768 u16
  const u16* UOTf = UcTf + 32768;             // 32768 u16

  const int bs = in_sizes[0] / 512;           // (BS,2,256)
  hipLaunchKernelGGL(hosvd_main, dim3(bs / TB), dim3(NTHR), 0, stream,
                     nh, te, bw, Ut, bt, bO, BTf, UcTf, UOTf, out);
}